// Round 12
// baseline (48.149 us; speedup 1.0000x reference)
//
#include <hip/hip_runtime.h>

#define SL1_BETA 0.01f
#define NSLOT   256            // one 128B line per slot (padded)
#define CHUNK   1024           // samples per block (4 per thread)
#define LDS_TT  0              // 1024 * 12 B = 12288
#define LDS_TE  12288          // 12288
#define LDS_BYTES 24576        // 24 KB -> 6 blocks/CU (LDS-limited, matches LB)

#define AS1(p) ((const __attribute__((address_space(1))) void*)(p))
#define AS3(p) ((__attribute__((address_space(3))) void*)(p))

__device__ __forceinline__ float smooth_l1(float x) {
    float d = fabsf(x);
    return (d < SL1_BETA) ? (0.5f * d * d / SL1_BETA) : (d - 0.5f * SL1_BETA);
}

__device__ __forceinline__ void quat_to_mat9(float4 q, float R[9]) {
    float r = q.x, i = q.y, j = q.z, k = q.w;
    float two_s = 2.0f / (r*r + i*i + j*j + k*k);
    R[0] = 1.0f - two_s * (j*j + k*k);
    R[1] = two_s * (i*j - k*r);
    R[2] = two_s * (i*k + j*r);
    R[3] = two_s * (i*j + k*r);
    R[4] = 1.0f - two_s * (i*i + k*k);
    R[5] = two_s * (j*k - i*r);
    R[6] = two_s * (i*k - j*r);
    R[7] = two_s * (j*k + i*r);
    R[8] = 1.0f - two_s * (i*i + j*j);
}

__device__ __forceinline__ void sample_loss(float4 q, float4 e,
                                            float t0, float t1, float t2,
                                            float p0, float p1, float p2,
                                            float& sr, float& st) {
    float R[9], P[9];
    quat_to_mat9(q, R);
    quat_to_mat9(e, P);

    // loss_r: sum smooth_l1(R^T P - I)
    #pragma unroll
    for (int i2 = 0; i2 < 3; ++i2) {
        #pragma unroll
        for (int j2 = 0; j2 < 3; ++j2) {
            float v = R[0*3 + i2] * P[0*3 + j2]
                    + R[1*3 + i2] * P[1*3 + j2]
                    + R[2*3 + i2] * P[2*3 + j2];
            sr += smooth_l1(v - (i2 == j2 ? 1.0f : 0.0f));
        }
    }

    // T_inv = -R^T t
    float Ti0 = -(R[0]*t0 + R[3]*t1 + R[6]*t2);
    float Ti1 = -(R[1]*t0 + R[4]*t1 + R[7]*t2);
    float Ti2 = -(R[2]*t0 + R[5]*t1 + R[8]*t2);

    st += smooth_l1(P[0]*Ti0 + P[1]*Ti1 + P[2]*Ti2 + p0);
    st += smooth_l1(P[3]*Ti0 + P[4]*Ti1 + P[5]*Ti2 + p1);
    st += smooth_l1(P[6]*Ti0 + P[7]*Ti1 + P[8]*Ti2 + p2);
}

// r9's hybrid one-shot block with CHUNK doubled to 1024:
// quats direct-to-VGPR (8 coalesced float4/thread-pair), tt/te via
// global_load_lds DMA (24 x 1KB ops, 6 per wave). Halves block turnovers
// and doubles per-block loads-in-flight vs r9. launch_bounds(256,6) keeps
// the VGPR cap at 85 (r11 lesson: never squeeze below the live set).
__global__ __launch_bounds__(256, 6) void euler_loss_kernel(
        const float*  __restrict__ tt,   // target_transl (b,3)
        const float4* __restrict__ tq,   // target_rot    (b,4)
        const float*  __restrict__ te,   // transl_err    (b,3)
        const float4* __restrict__ qe,   // rot_err       (b,4)
        double* __restrict__ acc, int b) {
    __shared__ __align__(16) unsigned char smem[LDS_BYTES];
    const int t    = threadIdx.x;
    const int lane = t & 63;
    const int wid  = t >> 6;
    const long long base = (long long)blockIdx.x * CHUNK;

    float sr = 0.0f, st = 0.0f;
    bool full = (base + CHUNK <= (long long)b);   // block-uniform
    if (full) {
        // ---- direct path: 8 coalesced float4 loads (4 samples/thread)
        float4 q0 = tq[base + t];
        float4 q1 = tq[base + t + 256];
        float4 q2 = tq[base + t + 512];
        float4 q3 = tq[base + t + 768];
        float4 e0 = qe[base + t];
        float4 e1 = qe[base + t + 256];
        float4 e2 = qe[base + t + 512];
        float4 e3 = qe[base + t + 768];

        // ---- DMA path: 24 x 1KB ops, 6 per wave (tt 12K | te 12K)
        const unsigned char* tt8 = (const unsigned char*)tt;
        const unsigned char* te8 = (const unsigned char*)te;
        #pragma unroll
        for (int u = 0; u < 6; ++u) {
            int o = wid * 6 + u;                     // wave-uniform, 0..23
            const unsigned char* src;
            if (o < 12) src = tt8 + base * 12 + (size_t)o        * 1024;
            else        src = te8 + base * 12 + (size_t)(o - 12) * 1024;
            __builtin_amdgcn_global_load_lds(AS1(src + (size_t)lane * 16),
                                             AS3(&smem[(size_t)o * 1024]),
                                             16, 0, 0);
        }
        __syncthreads();   // drains vmcnt(0): DMAs landed; q/e waits folded in

        const float* ttL = (const float*)&smem[LDS_TT];
        const float* teL = (const float*)&smem[LDS_TE];
        int c0 = t, c1 = t + 256, c2 = t + 512, c3 = t + 768;
        sample_loss(q0, e0, ttL[3*c0], ttL[3*c0+1], ttL[3*c0+2],
                    teL[3*c0], teL[3*c0+1], teL[3*c0+2], sr, st);
        sample_loss(q1, e1, ttL[3*c1], ttL[3*c1+1], ttL[3*c1+2],
                    teL[3*c1], teL[3*c1+1], teL[3*c1+2], sr, st);
        sample_loss(q2, e2, ttL[3*c2], ttL[3*c2+1], ttL[3*c2+2],
                    teL[3*c2], teL[3*c2+1], teL[3*c2+2], sr, st);
        sample_loss(q3, e3, ttL[3*c3], ttL[3*c3+1], ttL[3*c3+2],
                    teL[3*c3], teL[3*c3+1], teL[3*c3+2], sr, st);
    } else {
        // tail block (not hit at b = 2^21): direct global loads
        for (long long s = base + t; s < (long long)b; s += 256) {
            sample_loss(tq[s], qe[s],
                        tt[3*s], tt[3*s+1], tt[3*s+2],
                        te[3*s], te[3*s+1], te[3*s+2], sr, st);
        }
    }

    // wave (64-lane) reduction, one atomic pair per wave
    #pragma unroll
    for (int off = 32; off > 0; off >>= 1) {
        sr += __shfl_down(sr, off);
        st += __shfl_down(st, off);
    }
    if (lane == 0) {
        int slot = (blockIdx.x * 4 + wid) & (NSLOT - 1);
        double* sp = (double*)((unsigned char*)acc + (size_t)slot * 128);
        atomicAdd(&sp[0], (double)sr);
        atomicAdd(&sp[1], (double)st);
    }
}

__global__ __launch_bounds__(256) void euler_loss_finalize(
        const double* __restrict__ acc, float* __restrict__ out, int b) {
    int t = threadIdx.x;                 // 256 threads, one slot each
    const double* sp = (const double*)((const unsigned char*)acc + (size_t)t * 128);
    double sr = sp[0], st = sp[1];
    #pragma unroll
    for (int off = 32; off > 0; off >>= 1) {
        sr += __shfl_down(sr, off);
        st += __shfl_down(st, off);
    }
    __shared__ double s_r[4], s_t[4];
    int lane = t & 63, wid = t >> 6;
    if (lane == 0) { s_r[wid] = sr; s_t[wid] = st; }
    __syncthreads();
    if (t == 0) {
        double tr  = s_r[0] + s_r[1] + s_r[2] + s_r[3];
        double tts = s_t[0] + s_t[1] + s_t[2] + s_t[3];
        double inv_b = 1.0 / (double)b;
        double lr = tr * inv_b;
        double lt = tts * inv_b;
        out[0] = (float)(lr + lt);
        out[1] = (float)lt;
        out[2] = (float)lr;
    }
}

extern "C" void kernel_launch(void* const* d_in, const int* in_sizes, int n_in,
                              void* d_out, int out_size, void* d_ws, size_t ws_size,
                              hipStream_t stream) {
    // input order: point_clouds(0, unused), target_transl(1), target_rot(2),
    //              transl_err(3), rot_err(4)
    const float*  tt = (const float*)d_in[1];
    const float4* tq = (const float4*)d_in[2];
    const float*  te = (const float*)d_in[3];
    const float4* qe = (const float4*)d_in[4];
    float* out = (float*)d_out;
    int b = in_sizes[1] / 3;             // 2097152

    double* acc = (double*)d_ws;
    hipMemsetAsync(acc, 0, (size_t)NSLOT * 128, stream);   // 32 KB of slots

    int grid = (b + CHUNK - 1) / CHUNK;  // 2048 blocks at b = 2^21
    euler_loss_kernel<<<grid, 256, 0, stream>>>(tt, tq, te, qe, acc, b);
    euler_loss_finalize<<<1, 256, 0, stream>>>(acc, out, b);
}

// Round 13
// 28.223 us; speedup vs baseline: 1.7060x; 1.7060x over previous
//
#include <hip/hip_runtime.h>

#define SL1_BETA 0.01f
#define CHUNK   512            // samples per block
#define LDS_TT  0              // 512 * 12 B = 6144
#define LDS_TE  6144           // 6144
#define LDS_BYTES 12288        // 12 KB -> 6 blocks/CU at launch_bounds(256,6)

#define AS1(p) ((const __attribute__((address_space(1))) void*)(p))
#define AS3(p) ((__attribute__((address_space(3))) void*)(p))

__device__ __forceinline__ float smooth_l1(float x) {
    float d = fabsf(x);
    return (d < SL1_BETA) ? (0.5f * d * d / SL1_BETA) : (d - 0.5f * SL1_BETA);
}

__device__ __forceinline__ void quat_to_mat9(float4 q, float R[9]) {
    float r = q.x, i = q.y, j = q.z, k = q.w;
    float two_s = 2.0f / (r*r + i*i + j*j + k*k);
    R[0] = 1.0f - two_s * (j*j + k*k);
    R[1] = two_s * (i*j - k*r);
    R[2] = two_s * (i*k + j*r);
    R[3] = two_s * (i*j + k*r);
    R[4] = 1.0f - two_s * (i*i + k*k);
    R[5] = two_s * (j*k - i*r);
    R[6] = two_s * (i*k - j*r);
    R[7] = two_s * (j*k + i*r);
    R[8] = 1.0f - two_s * (i*i + j*j);
}

__device__ __forceinline__ void sample_loss(float4 q, float4 e,
                                            float t0, float t1, float t2,
                                            float p0, float p1, float p2,
                                            float& sr, float& st) {
    float R[9], P[9];
    quat_to_mat9(q, R);
    quat_to_mat9(e, P);

    // loss_r: sum smooth_l1(R^T P - I)
    #pragma unroll
    for (int i2 = 0; i2 < 3; ++i2) {
        #pragma unroll
        for (int j2 = 0; j2 < 3; ++j2) {
            float v = R[0*3 + i2] * P[0*3 + j2]
                    + R[1*3 + i2] * P[1*3 + j2]
                    + R[2*3 + i2] * P[2*3 + j2];
            sr += smooth_l1(v - (i2 == j2 ? 1.0f : 0.0f));
        }
    }

    // T_inv = -R^T t
    float Ti0 = -(R[0]*t0 + R[3]*t1 + R[6]*t2);
    float Ti1 = -(R[1]*t0 + R[4]*t1 + R[7]*t2);
    float Ti2 = -(R[2]*t0 + R[5]*t1 + R[8]*t2);

    st += smooth_l1(P[0]*Ti0 + P[1]*Ti1 + P[2]*Ti2 + p0);
    st += smooth_l1(P[3]*Ti0 + P[4]*Ti1 + P[5]*Ti2 + p1);
    st += smooth_l1(P[6]*Ti0 + P[7]*Ti1 + P[8]*Ti2 + p2);
}

// r9's hybrid one-shot block (quats direct-to-VGPR, tt/te via
// global_load_lds DMA), with the reduction tail made atomic-free:
// each block plain-stores one double2 partial to a unique slot
// (every slot written every call -> no memset dispatch, no atomics).
__global__ __launch_bounds__(256, 6) void euler_loss_kernel(
        const float*  __restrict__ tt,   // target_transl (b,3)
        const float4* __restrict__ tq,   // target_rot    (b,4)
        const float*  __restrict__ te,   // transl_err    (b,3)
        const float4* __restrict__ qe,   // rot_err       (b,4)
        double2* __restrict__ partial, int b) {
    __shared__ __align__(16) unsigned char smem[LDS_BYTES];
    __shared__ double s_r[4], s_t[4];
    const int t    = threadIdx.x;
    const int lane = t & 63;
    const int wid  = t >> 6;
    const long long base = (long long)blockIdx.x * CHUNK;

    float sr = 0.0f, st = 0.0f;
    bool full = (base + CHUNK <= (long long)b);   // block-uniform
    if (full) {
        // ---- direct path: 4 coalesced float4 loads (2 samples/thread)
        float4 q0 = tq[base + t];
        float4 q1 = tq[base + t + 256];
        float4 e0 = qe[base + t];
        float4 e1 = qe[base + t + 256];

        // ---- DMA path: 12 x 1KB ops, 3 per wave (tt 6K | te 6K)
        const unsigned char* tt8 = (const unsigned char*)tt;
        const unsigned char* te8 = (const unsigned char*)te;
        #pragma unroll
        for (int u = 0; u < 3; ++u) {
            int o = wid * 3 + u;                     // wave-uniform, 0..11
            const unsigned char* src;
            if (o < 6) src = tt8 + base * 12 + (size_t)o       * 1024;
            else       src = te8 + base * 12 + (size_t)(o - 6) * 1024;
            __builtin_amdgcn_global_load_lds(AS1(src + (size_t)lane * 16),
                                             AS3(&smem[(size_t)o * 1024]),
                                             16, 0, 0);
        }
        __syncthreads();   // drains vmcnt(0): DMAs landed; q/e waits folded in

        const float* ttL = (const float*)&smem[LDS_TT];
        const float* teL = (const float*)&smem[LDS_TE];
        int c0 = t, c1 = t + 256;
        sample_loss(q0, e0, ttL[3*c0], ttL[3*c0+1], ttL[3*c0+2],
                    teL[3*c0], teL[3*c0+1], teL[3*c0+2], sr, st);
        sample_loss(q1, e1, ttL[3*c1], ttL[3*c1+1], ttL[3*c1+2],
                    teL[3*c1], teL[3*c1+1], teL[3*c1+2], sr, st);
    } else {
        // tail block (not hit at b = 2^21): direct global loads
        for (long long s = base + t; s < (long long)b; s += 256) {
            sample_loss(tq[s], qe[s],
                        tt[3*s], tt[3*s+1], tt[3*s+2],
                        te[3*s], te[3*s+1], te[3*s+2], sr, st);
        }
    }

    // wave reduce -> LDS -> one plain double2 store per block (no atomics)
    #pragma unroll
    for (int off = 32; off > 0; off >>= 1) {
        sr += __shfl_down(sr, off);
        st += __shfl_down(st, off);
    }
    if (lane == 0) { s_r[wid] = (double)sr; s_t[wid] = (double)st; }
    __syncthreads();
    if (t == 0) {
        double2 p;
        p.x = s_r[0] + s_r[1] + s_r[2] + s_r[3];
        p.y = s_t[0] + s_t[1] + s_t[2] + s_t[3];
        partial[blockIdx.x] = p;
    }
}

// Reduce grid double2 partials -> out[3]. 256 threads, 16 independent
// unrolled loads per thread (full MLP), then wave/LDS reduce.
__global__ __launch_bounds__(256) void euler_loss_finalize(
        const double2* __restrict__ partial, float* __restrict__ out,
        int nblocks, int b) {
    int t = threadIdx.x;
    double sr = 0.0, st = 0.0;
    #pragma unroll 16
    for (int i = t; i < nblocks; i += 256) {
        double2 p = partial[i];
        sr += p.x;
        st += p.y;
    }
    #pragma unroll
    for (int off = 32; off > 0; off >>= 1) {
        sr += __shfl_down(sr, off);
        st += __shfl_down(st, off);
    }
    __shared__ double s_r[4], s_t[4];
    int lane = t & 63, wid = t >> 6;
    if (lane == 0) { s_r[wid] = sr; s_t[wid] = st; }
    __syncthreads();
    if (t == 0) {
        double tr  = s_r[0] + s_r[1] + s_r[2] + s_r[3];
        double tts = s_t[0] + s_t[1] + s_t[2] + s_t[3];
        double inv_b = 1.0 / (double)b;
        double lr = tr  * inv_b;
        double lt = tts * inv_b;
        out[0] = (float)(lr + lt);
        out[1] = (float)lt;
        out[2] = (float)lr;
    }
}

extern "C" void kernel_launch(void* const* d_in, const int* in_sizes, int n_in,
                              void* d_out, int out_size, void* d_ws, size_t ws_size,
                              hipStream_t stream) {
    // input order: point_clouds(0, unused), target_transl(1), target_rot(2),
    //              transl_err(3), rot_err(4)
    const float*  tt = (const float*)d_in[1];
    const float4* tq = (const float4*)d_in[2];
    const float*  te = (const float*)d_in[3];
    const float4* qe = (const float4*)d_in[4];
    float* out = (float*)d_out;
    int b = in_sizes[1] / 3;             // 2097152

    int grid = (b + CHUNK - 1) / CHUNK;  // 4096 blocks at b = 2^21
    double2* partial = (double2*)d_ws;   // grid * 16 B = 64 KB, fully
                                         // rewritten every call (no init)

    euler_loss_kernel<<<grid, 256, 0, stream>>>(tt, tq, te, qe, partial, b);
    euler_loss_finalize<<<1, 256, 0, stream>>>(partial, out, grid, b);
}